// Round 1
// 194.270 us; speedup vs baseline: 1.0291x; 1.0291x over previous
//
#include <hip/hip_runtime.h>
#include <stdint.h>

typedef __attribute__((ext_vector_type(8))) short short8;
typedef __attribute__((ext_vector_type(4))) float floatx4;

__device__ inline unsigned short f2bf(float x) {
  union { float f; unsigned int u; } v; v.f = x;
  unsigned int r = v.u + 0x7FFFu + ((v.u >> 16) & 1u);  // RNE
  return (unsigned short)(r >> 16);
}

// ---------------------------------------------------------------------------
// pack_all: one dispatch does both packs. (UNCHANGED — verified)
//   blocks [0,4096):    A_bf16[4096][2048] = bf16([x | h])
//   blocks [4096,6144): Wt_perm[4096][2048] = bf16(W^T) gate-interleaved:
//                       R = (h>>5)*128 + ((h>>4)&1)*64 + g*16 + (h&15)
// ---------------------------------------------------------------------------
__global__ void pack_all(const float* __restrict__ x, const float* __restrict__ h,
                         const float* __restrict__ wi, const float* __restrict__ wh,
                         unsigned short* __restrict__ A,
                         unsigned short* __restrict__ Wt) {
  int bid = blockIdx.x;
  int t = threadIdx.x;
  if (bid < 4096) {
    int idx = bid * 256 + t;
    int row = idx >> 8;
    int kc  = (idx & 255) << 3;
    const float* src = (kc < 1024) ? (x + (size_t)row * 1024 + kc)
                                   : (h + (size_t)row * 1024 + (kc - 1024));
    float4 a = ((const float4*)src)[0];
    float4 b = ((const float4*)src)[1];
    uint4 o;
    o.x = f2bf(a.x) | ((unsigned)f2bf(a.y) << 16);
    o.y = f2bf(a.z) | ((unsigned)f2bf(a.w) << 16);
    o.z = f2bf(b.x) | ((unsigned)f2bf(b.y) << 16);
    o.w = f2bf(b.z) | ((unsigned)f2bf(b.w) << 16);
    *(uint4*)(A + (size_t)row * 2048 + kc) = o;
  } else {
    __shared__ float tile[64][65];
    int b2 = bid - 4096;
    int kt = b2 & 31;
    int nt = b2 >> 5;
    int k0 = kt << 6, n0 = nt << 6;
    const float* src = (k0 < 1024) ? (wi + (size_t)k0 * 4096)
                                   : (wh + (size_t)(k0 - 1024) * 4096);
    int c4 = (t & 15) << 2, rr = t >> 4;
#pragma unroll
    for (int p = 0; p < 4; ++p) {
      int kk = rr + p * 16;
      float4 v = *(const float4*)(src + (size_t)kk * 4096 + n0 + c4);
      tile[kk][c4 + 0] = v.x; tile[kk][c4 + 1] = v.y;
      tile[kk][c4 + 2] = v.z; tile[kk][c4 + 3] = v.w;
    }
    __syncthreads();
    int k8 = (t & 7) << 3, nn = t >> 3;
#pragma unroll
    for (int p = 0; p < 2; ++p) {
      int n = n0 + nn + p * 32;          // global N index (gate*1024 + h)
      int hh = n & 1023, g = n >> 10;
      int R = ((hh >> 5) << 7) + (((hh >> 4) & 1) << 6) + (g << 4) + (hh & 15);
      int nl = nn + p * 32;
      uint4 o;
      o.x = f2bf(tile[k8 + 0][nl]) | ((unsigned)f2bf(tile[k8 + 1][nl]) << 16);
      o.y = f2bf(tile[k8 + 2][nl]) | ((unsigned)f2bf(tile[k8 + 3][nl]) << 16);
      o.z = f2bf(tile[k8 + 4][nl]) | ((unsigned)f2bf(tile[k8 + 5][nl]) << 16);
      o.w = f2bf(tile[k8 + 6][nl]) | ((unsigned)f2bf(tile[k8 + 7][nl]) << 16);
      *(uint4*)(Wt + (size_t)R * 2048 + k0 + k8) = o;
    }
  }
}

// ---------------------------------------------------------------------------
// gemm_lstm: 256x256 8-phase counted-vmcnt structure (m201 template).
//   BM=BN=256, BK=64, 512 thr (8 waves, 2Mx4N), per-wave 128x64 out.
//   LDS 128 KiB: A[2][256][64] + B[2][256][64] bf16, XOR-8 chunk swizzle
//   (both-sides involution — same math as the verified 128^2 kernel).
//   Per K-tile: 4 phases x {ds_read | 2x gl_lds | bar | lgkm0 | prio1
//   16 MFMA | prio0 | bar}. B-frags read once (phase 0) and held in regs.
//   Staging: A(t+1) in phases 0-1 (opposite buffer, idle since t-1),
//   B(t+2) in phases 2-3 (same buffer; B reg-captured at phase 0, two
//   barriers earlier -> no WAR hazard). Tile boundary: vmcnt(4) — the
//   newest B(t+2) pair stays in flight; never drain to 0 in-loop.
// ---------------------------------------------------------------------------
__device__ inline void gl_lds16(const void* g, void* l) {
  __builtin_amdgcn_global_load_lds(
      (const __attribute__((address_space(1))) void*)g,
      (__attribute__((address_space(3))) void*)l, 16, 0, 0);
}

__device__ inline float sigm(float x)  { return 1.0f / (1.0f + __expf(-x)); }
__device__ inline float tanhx(float x) { return 2.0f / (1.0f + __expf(-2.0f * x)) - 1.0f; }

#define MFMA_BF16 __builtin_amdgcn_mfma_f32_16x16x32_bf16

#define STAGE(SRC, DST)                                              \
  do {                                                               \
    gl_lds16((SRC) + rOff, (DST) + tid * 16);                        \
    gl_lds16((SRC) + rOff + (size_t)64 * 4096,                       \
             (DST) + tid * 16 + 8192);                               \
  } while (0)

// Phase for A-rows i=I0,I0+1 (all phases share reg-resident bf[4][2]).
#define PHASE(I0, STAGE_STMT, TAIL_STMT)                                      \
  {                                                                           \
    short8 a0k0 = *(const short8*)(pa + (I0) * 2048 + c0);                    \
    short8 a1k0 = *(const short8*)(pa + ((I0) + 1) * 2048 + c0);              \
    short8 a0k1 = *(const short8*)(pa + (I0) * 2048 + c1);                    \
    short8 a1k1 = *(const short8*)(pa + ((I0) + 1) * 2048 + c1);              \
    STAGE_STMT;                                                               \
    __builtin_amdgcn_s_barrier();                                             \
    asm volatile("s_waitcnt lgkmcnt(0)" ::: "memory");                        \
    __builtin_amdgcn_s_setprio(1);                                            \
    _Pragma("unroll")                                                         \
    for (int j = 0; j < 4; ++j) {                                             \
      acc[(I0)][j]     = MFMA_BF16(a0k0, bf[j][0], acc[(I0)][j], 0, 0, 0);    \
      acc[(I0) + 1][j] = MFMA_BF16(a1k0, bf[j][0], acc[(I0) + 1][j], 0, 0, 0);\
    }                                                                         \
    _Pragma("unroll")                                                         \
    for (int j = 0; j < 4; ++j) {                                             \
      acc[(I0)][j]     = MFMA_BF16(a0k1, bf[j][1], acc[(I0)][j], 0, 0, 0);    \
      acc[(I0) + 1][j] = MFMA_BF16(a1k1, bf[j][1], acc[(I0) + 1][j], 0, 0, 0);\
    }                                                                         \
    __builtin_amdgcn_s_setprio(0);                                            \
    TAIL_STMT;                                                                \
    __builtin_amdgcn_s_barrier();                                             \
  }

__global__ void __launch_bounds__(512, 2) gemm_lstm(
    const unsigned short* __restrict__ A,
    const unsigned short* __restrict__ Bt,
    const float* __restrict__ ct,
    const float* __restrict__ bi,
    const float* __restrict__ bh,
    float* __restrict__ out) {
  __shared__ __align__(16) char lds[131072];
  char* Al = lds;            // A: buf0 [0,32K), buf1 [32K,64K)
  char* Bl = lds + 65536;    // B: buf0, buf1

  const int tid  = threadIdx.x;
  const int lane = tid & 63;
  const int wave = tid >> 6;
  const int wm = wave >> 2;        // 0..1  (M half: 128 rows)
  const int wn = wave & 3;         // 0..3  (N quarter: 64 rows)

  // ---- XCD swizzle: 256 blocks, 8 XCDs; XCD g pins bx in {2g,2g+1}
  // (2 B-panels = 2 MB in its 4 MB L2), walks by sequentially. ----
  const int bid = blockIdx.x;
  const int gx = bid & 7;
  const int sx = bid >> 3;
  const int bx = (gx << 1) + (sx & 1);   // 0..15 (n block / 256)
  const int by = sx >> 1;                // 0..15 (m block / 256)
  const int m0 = by << 8;

  // ---- epilogue mapping + bias preload (gate = j, verified vs pack perm) --
  const int ec = lane & 15;
  const int h  = (bx << 6) + ((wn >> 1) << 5) + ((wn & 1) << 4) + ec;
  float bias[4];
#pragma unroll
  for (int j = 0; j < 4; ++j) bias[j] = bi[j * 1024 + h] + bh[j * 1024 + h];

  // ---- staging addressing: inverse-swizzled global source, linear LDS ----
  const int sr = tid >> 3;                                  // row 0..63
  const unsigned swz = (unsigned)(((tid & 7) ^ (sr & 7)) << 4);
  const size_t rOff = (size_t)sr * 4096 + swz;
  const char* aBase = (const char*)A  + (size_t)m0 * 4096;
  const char* bBase = (const char*)Bt + (size_t)(bx << 8) * 4096;

  // ---- LDS fragment addressing (swizzled read side) ----
  const int lr  = lane & 15;
  const int kq  = lane >> 4;          // k-chunk 0..3
  const int key = lane & 7;           // == row&7 for all frag rows
  const int c0  = (kq ^ key) << 4;          // k half 0
  const int c1  = ((4 + kq) ^ key) << 4;    // k half 1
  const int aRowOff = ((wm << 7) + lr) * 128;
  const int bRowOff = ((wn << 6) + lr) * 128;

  floatx4 acc[8][4] = {};

  // ---- prologue: tile0 full (B,A -> buf0), tile1 B -> buf1, then
  //      vmcnt(4) guarantees tile0 landed (tile1-B still in flight). ----
  STAGE(bBase, Bl);
  STAGE(bBase + (size_t)128 * 4096, Bl + 16384);
  STAGE(aBase, Al);
  STAGE(aBase + (size_t)128 * 4096, Al + 16384);
  STAGE(bBase + 128, Bl + 32768);
  STAGE(bBase + 128 + (size_t)128 * 4096, Bl + 32768 + 16384);
  asm volatile("s_waitcnt vmcnt(4)" ::: "memory");
  __builtin_amdgcn_s_barrier();

  for (int t = 0; t < 32; ++t) {
    const int buf = t & 1;
    const char* cA = Al + (buf << 15);
    const char* cB = Bl + (buf << 15);
    char* nA = Al + ((buf ^ 1) << 15);              // A(t+1) target
    char* sB = Bl + (buf << 15);                    // B(t+2) target (same buf)
    const char* aSrc = aBase + (size_t)(((t + 1) & 31) << 7);
    const char* bSrc = bBase + (size_t)(((t + 2) & 31) << 7);
    const char* pa = cA + aRowOff;
    const char* pb = cB + bRowOff;

    short8 bf[4][2];
    // ---- phase 0: all B-frags (8 reads) + A i=0,1; stage A-lo(t+1) ----
    {
#pragma unroll
      for (int j = 0; j < 4; ++j) {
        bf[j][0] = *(const short8*)(pb + j * 2048 + c0);
        bf[j][1] = *(const short8*)(pb + j * 2048 + c1);
      }
      short8 a0k0 = *(const short8*)(pa + c0);
      short8 a1k0 = *(const short8*)(pa + 2048 + c0);
      short8 a0k1 = *(const short8*)(pa + c1);
      short8 a1k1 = *(const short8*)(pa + 2048 + c1);
      STAGE(aSrc, nA);
      __builtin_amdgcn_s_barrier();
      asm volatile("s_waitcnt lgkmcnt(0)" ::: "memory");
      __builtin_amdgcn_s_setprio(1);
#pragma unroll
      for (int j = 0; j < 4; ++j) {
        acc[0][j] = MFMA_BF16(a0k0, bf[j][0], acc[0][j], 0, 0, 0);
        acc[1][j] = MFMA_BF16(a1k0, bf[j][0], acc[1][j], 0, 0, 0);
      }
#pragma unroll
      for (int j = 0; j < 4; ++j) {
        acc[0][j] = MFMA_BF16(a0k1, bf[j][1], acc[0][j], 0, 0, 0);
        acc[1][j] = MFMA_BF16(a1k1, bf[j][1], acc[1][j], 0, 0, 0);
      }
      __builtin_amdgcn_s_setprio(0);
      __builtin_amdgcn_s_barrier();
    }
    // ---- phase 1: A i=2,3; stage A-hi(t+1) ----
    PHASE(2, STAGE(aSrc + (size_t)128 * 4096, nA + 16384), );
    // ---- phase 2: A i=4,5; stage B-lo(t+2) (cB; B reg-captured ph0) ----
    PHASE(4, STAGE(bSrc, sB), );
    // ---- phase 3: A i=6,7; stage B-hi(t+2); boundary vmcnt(4) ----
    PHASE(6, STAGE(bSrc + (size_t)128 * 4096, sB + 16384),
          asm volatile("s_waitcnt vmcnt(4)" ::: "memory"));
  }

  // ---- fused LSTM epilogue: batch ct loads, then lane-local gates ----
  const int er = (lane >> 4) << 2;
  float cv[8][4];
#pragma unroll
  for (int i = 0; i < 8; ++i)
#pragma unroll
    for (int rg = 0; rg < 4; ++rg) {
      int row = m0 + (wm << 7) + i * 16 + er + rg;
      cv[i][rg] = ct[(size_t)row * 1024 + h];
    }
#pragma unroll
  for (int i = 0; i < 8; ++i) {
#pragma unroll
    for (int rg = 0; rg < 4; ++rg) {
      int row = m0 + (wm << 7) + i * 16 + er + rg;
      size_t o = (size_t)row * 1024 + h;
      float iv = sigm(acc[i][0][rg] + bias[0]);
      float fv = sigm(acc[i][1][rg] + bias[1]);
      float gv = tanhx(acc[i][2][rg] + bias[2]);
      float ov = sigm(acc[i][3][rg] + bias[3]);
      float cn = fv * cv[i][rg] + iv * gv;
      out[o] = ov * tanhx(cn);
      out[4194304 + o] = cn;
    }
  }
}

// ---------------------------------------------------------------------------
extern "C" void kernel_launch(void* const* d_in, const int* in_sizes, int n_in,
                              void* d_out, int out_size, void* d_ws, size_t ws_size,
                              hipStream_t stream) {
  const float* x  = (const float*)d_in[0];
  const float* ht = (const float*)d_in[1];
  const float* ct = (const float*)d_in[2];
  const float* wi = (const float*)d_in[3];
  const float* wh = (const float*)d_in[4];
  const float* bi = (const float*)d_in[5];
  const float* bh = (const float*)d_in[6];
  float* out = (float*)d_out;

  char* ws = (char*)d_ws;
  unsigned short* Abf = (unsigned short*)ws;                 // 16 MiB
  unsigned short* Wbf = (unsigned short*)(ws + (16u << 20)); // 16 MiB

  pack_all<<<6144, 256, 0, stream>>>(x, ht, wi, wh, Abf, Wbf);
  gemm_lstm<<<256, 512, 0, stream>>>(Abf, Wbf, ct, bi, bh, out);
}